// Round 18
// baseline (131.523 us; speedup 1.0000x reference)
//
#include <hip/hip_runtime.h>
#include <math.h>

#define DD 64      // feature dim
#define MM 128     // time points per path
#define PSTR 66    // packed plane row stride (u32): reads (lane+2r)%32 = 2-way free
#define PWORDS (16 * PSTR)   // 1056 u32 = 4224 B per stream plane

typedef float  f32x4v __attribute__((ext_vector_type(4)));
typedef __bf16 bf16x8 __attribute__((ext_vector_type(8)));

#define FOR8(F) F(0) F(1) F(2) F(3) F(4) F(5) F(6) F(7)

union FragU { unsigned int u[4]; bf16x8 v; };

// RNE f32x2 -> packed bf16x2
__device__ __forceinline__ unsigned cvtpk(float lo, float hi) {
    unsigned r;
    asm("v_cvt_pk_bf16_f32 %0, %1, %2" : "=v"(r) : "v"(lo), "v"(hi));
    return r;
}

// quad_perm [1,0,3,2]: swap adjacent lanes (lane ^ 1)
__device__ __forceinline__ float qswap(float x) {
    int t = __builtin_amdgcn_update_dpp(0, __float_as_int(x), 0xB1, 0xF, 0xF, true);
    return __int_as_float(t);
}

// bf16 frag of (row1 - row0), 8 consecutive floats (hi bits, RNE)
__device__ __forceinline__ bf16x8 dfrag_hi(const float* __restrict__ r0,
                                           const float* __restrict__ r1) {
    float4 a0 = *(const float4*)r0, a1 = *(const float4*)(r0 + 4);
    float4 b0 = *(const float4*)r1, b1 = *(const float4*)(r1 + 4);
    FragU f;
    f.u[0] = cvtpk(b0.x - a0.x, b0.y - a0.y);
    f.u[1] = cvtpk(b0.z - a0.z, b0.w - a0.w);
    f.u[2] = cvtpk(b1.x - a1.x, b1.y - a1.y);
    f.u[3] = cvtpk(b1.z - a1.z, b1.w - a1.w);
    return f.v;
}

template<int CTRL, int RM, bool BC>
__device__ __forceinline__ float dpp_add(float x) {
    int t = __builtin_amdgcn_update_dpp(0, __float_as_int(x), CTRL, RM, 0xf, BC);
    return x + __int_as_float(t);
}

// 4 INDEPENDENT wave64 inclusive scans, levels interleaved across streams so
// the 3 other chains fill each chain's DPP hazard slots.
__device__ __forceinline__ void scan4(float& x0, float& x1, float& x2, float& x3) {
#define LVL(CTRL, RM, BC) \
    x0 = dpp_add<CTRL, RM, BC>(x0); \
    x1 = dpp_add<CTRL, RM, BC>(x1); \
    x2 = dpp_add<CTRL, RM, BC>(x2); \
    x3 = dpp_add<CTRL, RM, BC>(x3);
    LVL(0x111, 0xf, true)   // row_shr:1
    LVL(0x112, 0xf, true)   // row_shr:2
    LVL(0x114, 0xf, true)   // row_shr:4
    LVL(0x118, 0xf, true)   // row_shr:8
    LVL(0x142, 0xa, false)  // row_bcast:15 -> rows 1,3
    LVL(0x143, 0xc, false)  // row_bcast:31 -> rows 2,3
#undef LVL
}

// ROUND 18 = ROUND 17 with the spill eliminated (r17: WRITE_SIZE 8.1 MB, FETCH
// 28.6 MB, 40 ms cold dispatch = scratch alloc -> the 4-stream live set ~200
// regs blew the (64,3) ~170 cap; the scan-ILP hypothesis was never tested).
//  (1) __launch_bounds__(64,2): 256-reg cap (r16 proved residency >2/SIMD is
//      worthless, so the occupancy cost is free);
//  (2) staging restructured PER-STREAM (load stream s's A-frags, run its 8
//      CTSTEPs, release): peak A liveness 32 -> 8 regs, live ~150.
// Scan (scan4 interleave), packed-bf16 planes, decode, reducer: identical r17.
__global__ __launch_bounds__(64, 2) void sig_goursat_kernel(
        const float* __restrict__ X, const float* __restrict__ Y,
        float* __restrict__ Kout)
{
#define OFFB(bb) (((((bb) >> 2) + 1)) * (2 * ((bb) >> 2) + ((bb) & 3)))
    const int t = blockIdx.x;
    int g, b, j;
    if (t < 1088) {                    // symmetric grams, column 4-packed tri
        g = t < 544 ? 0 : 1;
        const int u = t - g * 544;
        int bb = (int)sqrtf(8.0f * (float)u + 1.0f);
        if (bb > 63) bb = 63;
        while (bb > 0  && OFFB(bb) > u) --bb;
        while (bb < 63 && OFFB(bb + 1) <= u) ++bb;
        b = bb;
        j = u - OFFB(bb);
    } else {
        const int u = t - 1088;
        g = 2; b = u & 63; j = u >> 6;
    }
    const int a0r = 4 * j, a1r = 4 * j + 1, a2r = 4 * j + 2, a3r = 4 * j + 3;
    const bool tri = (g < 2);
    const int a0 = (tri && a0r > b) ? b : a0r;
    const int a1 = (tri && a1r > b) ? b : a1r;
    const int a2 = (tri && a2r > b) ? b : a2r;
    const int a3 = (tri && a3r > b) ? b : a3r;

    const float* __restrict__ Ub = (g == 1 ? Y : X);
    const float* __restrict__ U0 = Ub + (size_t)a0 * (MM * DD);
    const float* __restrict__ U1 = Ub + (size_t)a1 * (MM * DD);
    const float* __restrict__ U2 = Ub + (size_t)a2 * (MM * DD);
    const float* __restrict__ U3 = Ub + (size_t)a3 * (MM * DD);
    const float* __restrict__ V  = (g == 0 ? X : Y) + (size_t)b * (MM * DD);

    const int lane = threadIdx.x;
    const int l15  = lane & 15;
    const int k8   = (lane >> 4) * 8;         // k-offset of this lane's frag
    const int rowg = (lane >> 4) * 4;         // C/D row group base
    const int par  = l15 & 1;

    __shared__ unsigned incL[4 * PWORDS];     // 4 packed-bf16 stream planes
    unsigned* __restrict__ pl0 = incL;
    unsigned* __restrict__ pl1 = incL + PWORDS;
    unsigned* __restrict__ pl2 = incL + 2 * PWORDS;
    unsigned* __restrict__ pl3 = incL + 3 * PWORDS;

    // ---- shared B-frag register table: 16 named bf16x8 (64 regs) ----
#define TBDECL(ct) bf16x8 tb0_##ct, tb1_##ct;
    FOR8(TBDECL)
#define TBUILD(ct) { int brow_ = ct * 16 + l15; if (brow_ > 126) brow_ = 126; \
        const float* vp_ = V + (size_t)brow_ * DD + k8; \
        tb0_##ct = dfrag_hi(vp_,      vp_ + DD); \
        tb1_##ct = dfrag_hi(vp_ + 32, vp_ + DD + 32); }
    FOR8(TBUILD)

    float KL0_0 = 1.f, KL1_0 = 1.f, KL0_1 = 1.f, KL1_1 = 1.f;
    float KL0_2 = 1.f, KL1_2 = 1.f, KL0_3 = 1.f, KL1_3 = 1.f;

    // packed writer (r13-verified): even l15 lanes own rows rowg+0/1,
    // odd own rowg+2/3; word = row*PSTR + ct*8 + (l15>>1)
    const int wA = (rowg + 2 * par) * PSTR + (l15 >> 1);
    const int wB = wA + PSTR;

    // one col-tile of one stream: frags ak0_/ak1_ and plane pls in scope
#define CTSTEPS(ct) { \
        f32x4v c = {0.f, 0.f, 0.f, 0.f}; \
        c = __builtin_amdgcn_mfma_f32_16x16x32_bf16(ak0_, tb0_##ct, c, 0, 0, 0); \
        c = __builtin_amdgcn_mfma_f32_16x16x32_bf16(ak1_, tb1_##ct, c, 0, 0, 0); \
        const float n0 = qswap(c[0]); const float n1 = qswap(c[1]); \
        const float n2 = qswap(c[2]); const float n3 = qswap(c[3]); \
        const float loA = par ? n2 : c[0]; const float hiA = par ? c[2] : n0; \
        const float loB = par ? n3 : c[1]; const float hiB = par ? c[3] : n1; \
        pls[wA + (ct) * 8] = cvtpk(loA, hiA); \
        pls[wB + (ct) * 8] = cvtpk(loB, hiB); }

    // stage one stream's band: load A-frags (8 regs), 8 col-tiles, release
#define STAGE1(s) { \
        const float* ap_ = U##s + aoff; \
        bf16x8 ak0_ = dfrag_hi(ap_,      ap_ + DD); \
        bf16x8 ak1_ = dfrag_hi(ap_ + 32, ap_ + DD + 32); \
        unsigned* __restrict__ pls = pl##s; \
        FOR8(CTSTEPS) }

    // quad scan row: unpack 4 packed words, 4 independent scans interleaved
#define SQUAD(w0_, w1_, w2_, w3_) { \
        const float iE0 = __uint_as_float((w0_) << 16); \
        const float iO0 = __uint_as_float((w0_) & 0xffff0000u); \
        const float iE1 = __uint_as_float((w1_) << 16); \
        const float iO1 = __uint_as_float((w1_) & 0xffff0000u); \
        const float iE2 = __uint_as_float((w2_) << 16); \
        const float iO2 = __uint_as_float((w2_) & 0xffff0000u); \
        const float iE3 = __uint_as_float((w3_) << 16); \
        const float iO3 = __uint_as_float((w3_) & 0xffff0000u); \
        const float m00 = iE0 * KL0_0, m10 = iO0 * KL1_0; \
        const float m01 = iE1 * KL0_1, m11 = iO1 * KL1_1; \
        const float m02 = iE2 * KL0_2, m12 = iO2 * KL1_2; \
        const float m03 = iE3 * KL0_3, m13 = iO3 * KL1_3; \
        const float q0 = m00 + m10, q1 = m01 + m11; \
        const float q2 = m02 + m12, q3 = m03 + m13; \
        float s0 = q0, s1 = q1, s2 = q2, s3 = q3; \
        scan4(s0, s1, s2, s3); \
        const float ex0 = s0 - q0, ex1 = s1 - q1; \
        const float ex2 = s2 - q2, ex3 = s3 - q3; \
        KL1_0 += ex0 + m00;  KL0_0 += ex0; \
        KL1_1 += ex1 + m01;  KL0_1 += ex1; \
        KL1_2 += ex2 + m02;  KL0_2 += ex2; \
        KL1_3 += ex3 + m03;  KL0_3 += ex3; }

    const unsigned* __restrict__ pr0 = pl0 + lane;
    const unsigned* __restrict__ pr1 = pl1 + lane;
    const unsigned* __restrict__ pr2 = pl2 + lane;
    const unsigned* __restrict__ pr3 = pl3 + lane;

    for (int band = 0; band < 8; ++band) {
        // ---- stage 4 streams, one at a time (peak A liveness = 8 regs) ----
        int arow = band * 16 + l15; if (arow > 126) arow = 126;
        const size_t aoff = (size_t)arow * DD + k8;
        STAGE1(0) STAGE1(1) STAGE1(2) STAGE1(3)

        // ---- quad Goursat scan, depth-2 LDS prefetch per stream ----
        unsigned e0 = pr0[0],    e1 = pr1[0],    e2 = pr2[0],    e3 = pr3[0];
        unsigned f0 = pr0[PSTR], f1 = pr1[PSTR], f2 = pr2[PSTR], f3 = pr3[PSTR];
        #pragma unroll
        for (int r = 0; r < 13; ++r) {
            unsigned n0 = pr0[(r + 2) * PSTR];
            unsigned n1 = pr1[(r + 2) * PSTR];
            unsigned n2 = pr2[(r + 2) * PSTR];
            unsigned n3 = pr3[(r + 2) * PSTR];
            SQUAD(e0, e1, e2, e3)
            e0 = f0; e1 = f1; e2 = f2; e3 = f3;
            f0 = n0; f1 = n1; f2 = n2; f3 = n3;
        }
        if (band < 7) {
            unsigned n0 = pr0[15 * PSTR], n1 = pr1[15 * PSTR];
            unsigned n2 = pr2[15 * PSTR], n3 = pr3[15 * PSTR];
            SQUAD(e0, e1, e2, e3)                 // row 13
            e0 = f0; e1 = f1; e2 = f2; e3 = f3;
            f0 = n0; f1 = n1; f2 = n2; f3 = n3;
            SQUAD(e0, e1, e2, e3)                 // row 14
            SQUAD(f0, f1, f2, f3)                 // row 15
        } else {
            SQUAD(e0, e1, e2, e3)                 // row 13
            SQUAD(f0, f1, f2, f3)                 // row 14 (p=127 phantom)
        }
    }

    if (lane == 63) {
        float* kg = Kout + (size_t)g * 4096;
        kg[a0 * 64 + b] = KL1_0;
        if (!tri || a1r <= b) kg[a1 * 64 + b] = KL1_1;
        if (!tri || a2r <= b) kg[a2 * 64 + b] = KL1_2;
        if (!tri || a3r <= b) kg[a3 * 64 + b] = KL1_3;
    }
}

// Deterministic weighted reduction + the mean((X0-Y0)^2) term.
__global__ void sig_reduce_kernel(const float* __restrict__ X,
                                  const float* __restrict__ Y,
                                  const float* __restrict__ Kws,
                                  float* __restrict__ out)
{
    const int t = threadIdx.x;
    double accK = 0.0, acc2 = 0.0;
    for (int i = t; i < 4096; i += 256) {
        const int a = i >> 6, b = i & 63;
        if (a <= b) {
            const double w = (a == b) ? 1.0 : 2.0;
            accK += w * (double)Kws[i];           // XX
            accK += w * (double)Kws[4096 + i];    // YY
        }
        accK -= 2.0 * (double)Kws[8192 + i];      // XY
        const float df = X[(size_t)a * (MM * DD) + b] - Y[(size_t)a * (MM * DD) + b];
        acc2 += (double)df * (double)df;
    }
    __shared__ double red[256];
    red[t] = accK / 4096.0 + acc2 / 4096.0;
    __syncthreads();
    for (int s = 128; s > 0; s >>= 1) {
        if (t < s) red[t] += red[t + s];
        __syncthreads();
    }
    if (t == 0) out[0] = (float)red[0];
}

extern "C" void kernel_launch(void* const* d_in, const int* in_sizes, int n_in,
                              void* d_out, int out_size, void* d_ws, size_t ws_size,
                              hipStream_t stream) {
    const float* X = (const float*)d_in[0];
    const float* Y = (const float*)d_in[1];
    float* Kws = (float*)d_ws;          // 3 * 4096 floats
    float* out = (float*)d_out;

    sig_goursat_kernel<<<dim3(2112), dim3(64), 0, stream>>>(X, Y, Kws);
    sig_reduce_kernel<<<dim3(1), dim3(256), 0, stream>>>(X, Y, Kws, out);
}

// Round 19
// 129.112 us; speedup vs baseline: 1.0187x; 1.0187x over previous
//
#include <hip/hip_runtime.h>
#include <math.h>

#define DD 64      // feature dim
#define MM 128     // time points per path
#define PSTR 66    // packed plane row stride (u32): reads (lane+2r)%32 = 2-way free
#define PWORDS (16 * PSTR)   // 1056 u32 = 4224 B per stream plane

typedef float  f32x4v __attribute__((ext_vector_type(4)));
typedef __bf16 bf16x8 __attribute__((ext_vector_type(8)));

#define FOR8(F) F(0) F(1) F(2) F(3) F(4) F(5) F(6) F(7)

union FragU { unsigned int u[4]; bf16x8 v; };

// RNE f32x2 -> packed bf16x2
__device__ __forceinline__ unsigned cvtpk(float lo, float hi) {
    unsigned r;
    asm("v_cvt_pk_bf16_f32 %0, %1, %2" : "=v"(r) : "v"(lo), "v"(hi));
    return r;
}

// quad_perm [1,0,3,2]: swap adjacent lanes (lane ^ 1)
__device__ __forceinline__ float qswap(float x) {
    int t = __builtin_amdgcn_update_dpp(0, __float_as_int(x), 0xB1, 0xF, 0xF, true);
    return __int_as_float(t);
}

// bf16 frag of (row1 - row0), 8 consecutive floats (hi bits, RNE)
__device__ __forceinline__ bf16x8 dfrag_hi(const float* __restrict__ r0,
                                           const float* __restrict__ r1) {
    float4 a0 = *(const float4*)r0, a1 = *(const float4*)(r0 + 4);
    float4 b0 = *(const float4*)r1, b1 = *(const float4*)(r1 + 4);
    FragU f;
    f.u[0] = cvtpk(b0.x - a0.x, b0.y - a0.y);
    f.u[1] = cvtpk(b0.z - a0.z, b0.w - a0.w);
    f.u[2] = cvtpk(b1.x - a1.x, b1.y - a1.y);
    f.u[3] = cvtpk(b1.z - a1.z, b1.w - a1.w);
    return f.v;
}

template<int CTRL, int RM, bool BC>
__device__ __forceinline__ float dpp_add(float x) {
    int t = __builtin_amdgcn_update_dpp(0, __float_as_int(x), CTRL, RM, 0xf, BC);
    return x + __int_as_float(t);
}

// 2 independent wave64 inclusive scans, levels interleaved
__device__ __forceinline__ void scan2(float& x0, float& x1) {
#define LVL(CTRL, RM, BC) \
    x0 = dpp_add<CTRL, RM, BC>(x0); \
    x1 = dpp_add<CTRL, RM, BC>(x1);
    LVL(0x111, 0xf, true)   // row_shr:1
    LVL(0x112, 0xf, true)   // row_shr:2
    LVL(0x114, 0xf, true)   // row_shr:4
    LVL(0x118, 0xf, true)   // row_shr:8
    LVL(0x142, 0xa, false)  // row_bcast:15 -> rows 1,3
    LVL(0x143, 0xc, false)  // row_bcast:31 -> rows 2,3
#undef LVL
}

// ROUND 19: r11's structure (2 pairs/wave sharing the V-column B-table, dual
// scan -- lowest measured VALU/pair) with its LDS footprint halved via r13's
// verified packed-bf16 planes (2 x 4.2 KB = 8.4 KB/block vs 16.9), and the
// launch bound set to the MEASURED register need (r11 compiled to 84 VGPRs;
// (64,4) caps at 128). LDS now allows 18 blocks/CU; grid supplies 16.25
// -> ~4 waves/SIMD at identical per-pair work (r16/r13/r18's regressions were
// per-pair WORK increases, not TLP failures). Per-stream staging keeps A-frag
// liveness at 8 regs. Sentinels: WRITE_SIZE ~0.21 MB, VGPR <= 128.
__global__ __launch_bounds__(64, 4) void sig_goursat_kernel(
        const float* __restrict__ X, const float* __restrict__ Y,
        float* __restrict__ Kout)
{
    const int bid = blockIdx.x;
    int g, a0, a1, bcol;
    bool dup = false;
    if (bid < 2112) {                  // symmetric grams, column-paired tri
        g = bid < 1056 ? 0 : 1;
        const int t = bid - g * 1056;
        bcol = (int)(2.0f * sqrtf((float)t + 1.0f));
        if (bcol > 63) bcol = 63;
        while (bcol > 0  && ((bcol + 1) * (bcol + 1)) / 4 > t) --bcol;
        while (bcol < 63 && ((bcol + 2) * (bcol + 2)) / 4 <= t) ++bcol;
        const int j = t - ((bcol + 1) * (bcol + 1)) / 4;
        a0 = 2 * j; a1 = 2 * j + 1;
        if (a1 > bcol) { a1 = a0; dup = true; }
    } else {
        const int t = bid - 2112;
        g = 2; bcol = t & 63;
        a0 = (t >> 6) * 2; a1 = a0 + 1;
    }

    const float* __restrict__ Ub = (g == 1 ? Y : X);
    const float* __restrict__ U0 = Ub + (size_t)a0 * (MM * DD);
    const float* __restrict__ U1 = Ub + (size_t)a1 * (MM * DD);
    const float* __restrict__ V  = (g == 0 ? X : Y) + (size_t)bcol * (MM * DD);

    const int lane = threadIdx.x;
    const int l15  = lane & 15;
    const int k8   = (lane >> 4) * 8;         // k-offset of this lane's frag
    const int rowg = (lane >> 4) * 4;         // C/D row group base
    const int par  = l15 & 1;

    __shared__ unsigned incL[2 * PWORDS];     // 2 packed-bf16 stream planes
    unsigned* __restrict__ pl0 = incL;
    unsigned* __restrict__ pl1 = incL + PWORDS;

    // ---- shared B-frag register table: 16 named bf16x8 (64 regs) ----
#define TBDECL(ct) bf16x8 tb0_##ct, tb1_##ct;
    FOR8(TBDECL)
#define TBUILD(ct) { int brow_ = ct * 16 + l15; if (brow_ > 126) brow_ = 126; \
        const float* vp_ = V + (size_t)brow_ * DD + k8; \
        tb0_##ct = dfrag_hi(vp_,      vp_ + DD); \
        tb1_##ct = dfrag_hi(vp_ + 32, vp_ + DD + 32); }
    FOR8(TBUILD)

    float KL0_0 = 1.f, KL1_0 = 1.f;           // stream 0: K[0][2l], K[0][2l+1]
    float KL0_1 = 1.f, KL1_1 = 1.f;           // stream 1

    // packed writer (r13-verified): even l15 lanes own rows rowg+0/1,
    // odd own rowg+2/3; word = row*PSTR + ct*8 + (l15>>1)
    const int wA = (rowg + 2 * par) * PSTR + (l15 >> 1);
    const int wB = wA + PSTR;

    // one col-tile of one stream: frags ak0_/ak1_ and plane pls in scope
#define CTSTEPS(ct) { \
        f32x4v c = {0.f, 0.f, 0.f, 0.f}; \
        c = __builtin_amdgcn_mfma_f32_16x16x32_bf16(ak0_, tb0_##ct, c, 0, 0, 0); \
        c = __builtin_amdgcn_mfma_f32_16x16x32_bf16(ak1_, tb1_##ct, c, 0, 0, 0); \
        const float n0 = qswap(c[0]); const float n1 = qswap(c[1]); \
        const float n2 = qswap(c[2]); const float n3 = qswap(c[3]); \
        const float loA = par ? n2 : c[0]; const float hiA = par ? c[2] : n0; \
        const float loB = par ? n3 : c[1]; const float hiB = par ? c[3] : n1; \
        pls[wA + (ct) * 8] = cvtpk(loA, hiA); \
        pls[wB + (ct) * 8] = cvtpk(loB, hiB); }

    // stage one stream's band: load A-frags (8 regs), 8 col-tiles, release
#define STAGE1(s) { \
        const float* ap_ = U##s + aoff; \
        bf16x8 ak0_ = dfrag_hi(ap_,      ap_ + DD); \
        bf16x8 ak1_ = dfrag_hi(ap_ + 32, ap_ + DD + 32); \
        unsigned* __restrict__ pls = pl##s; \
        FOR8(CTSTEPS) }

    // dual scan row: unpack 2 packed words, 2 interleaved scans, update
#define SDUAL(w0_, w1_) { \
        const float iE0 = __uint_as_float((w0_) << 16); \
        const float iO0 = __uint_as_float((w0_) & 0xffff0000u); \
        const float iE1 = __uint_as_float((w1_) << 16); \
        const float iO1 = __uint_as_float((w1_) & 0xffff0000u); \
        const float m00 = iE0 * KL0_0, m10 = iO0 * KL1_0; \
        const float m01 = iE1 * KL0_1, m11 = iO1 * KL1_1; \
        const float q0 = m00 + m10, q1 = m01 + m11; \
        float s0 = q0, s1 = q1; \
        scan2(s0, s1); \
        const float ex0 = s0 - q0, ex1 = s1 - q1; \
        KL1_0 += ex0 + m00;  KL0_0 += ex0; \
        KL1_1 += ex1 + m01;  KL0_1 += ex1; }

    const unsigned* __restrict__ pr0 = pl0 + lane;
    const unsigned* __restrict__ pr1 = pl1 + lane;

    for (int band = 0; band < 8; ++band) {
        // ---- stage both streams, one at a time (A liveness = 8 regs) ----
        int arow = band * 16 + l15; if (arow > 126) arow = 126;
        const size_t aoff = (size_t)arow * DD + k8;
        STAGE1(0) STAGE1(1)

        // ---- dual Goursat scan, depth-2 LDS prefetch per stream ----
        unsigned e0 = pr0[0],    e1 = pr1[0];
        unsigned f0 = pr0[PSTR], f1 = pr1[PSTR];
        #pragma unroll
        for (int r = 0; r < 13; ++r) {
            unsigned n0 = pr0[(r + 2) * PSTR];
            unsigned n1 = pr1[(r + 2) * PSTR];
            SDUAL(e0, e1)
            e0 = f0; e1 = f1; f0 = n0; f1 = n1;
        }
        if (band < 7) {
            unsigned n0 = pr0[15 * PSTR], n1 = pr1[15 * PSTR];
            SDUAL(e0, e1)                         // row 13
            e0 = f0; e1 = f1; f0 = n0; f1 = n1;
            SDUAL(e0, e1)                         // row 14
            SDUAL(f0, f1)                         // row 15
        } else {
            SDUAL(e0, e1)                         // row 13
            SDUAL(f0, f1)                         // row 14 (p=127 phantom)
        }
    }

    if (lane == 63) {
        float* kg = Kout + (size_t)g * 4096;
        kg[a0 * 64 + bcol] = KL1_0;               // K[127][127], stream 0
        if (!dup) kg[a1 * 64 + bcol] = KL1_1;     // stream 1
    }
}

// Deterministic weighted reduction + the mean((X0-Y0)^2) term.
__global__ void sig_reduce_kernel(const float* __restrict__ X,
                                  const float* __restrict__ Y,
                                  const float* __restrict__ Kws,
                                  float* __restrict__ out)
{
    const int t = threadIdx.x;
    double accK = 0.0, acc2 = 0.0;
    for (int i = t; i < 4096; i += 256) {
        const int a = i >> 6, b = i & 63;
        if (a <= b) {
            const double w = (a == b) ? 1.0 : 2.0;
            accK += w * (double)Kws[i];           // XX
            accK += w * (double)Kws[4096 + i];    // YY
        }
        accK -= 2.0 * (double)Kws[8192 + i];      // XY
        const float df = X[(size_t)a * (MM * DD) + b] - Y[(size_t)a * (MM * DD) + b];
        acc2 += (double)df * (double)df;
    }
    __shared__ double red[256];
    red[t] = accK / 4096.0 + acc2 / 4096.0;
    __syncthreads();
    for (int s = 128; s > 0; s >>= 1) {
        if (t < s) red[t] += red[t + s];
        __syncthreads();
    }
    if (t == 0) out[0] = (float)red[0];
}

extern "C" void kernel_launch(void* const* d_in, const int* in_sizes, int n_in,
                              void* d_out, int out_size, void* d_ws, size_t ws_size,
                              hipStream_t stream) {
    const float* X = (const float*)d_in[0];
    const float* Y = (const float*)d_in[1];
    float* Kws = (float*)d_ws;          // 3 * 4096 floats
    float* out = (float*)d_out;

    sig_goursat_kernel<<<dim3(4160), dim3(64), 0, stream>>>(X, Y, Kws);
    sig_reduce_kernel<<<dim3(1), dim3(256), 0, stream>>>(X, Y, Kws, out);
}